// Round 9
// baseline (2931.845 us; speedup 1.0000x reference)
//
#include <hip/hip_runtime.h>

// LSTM: H=1024, B=1024, S=128 (T=127 steps), E=6, V=3, C=10.
// R21 = R19 VERBATIM (passed: persistent, LDS-resident weights, 256-flag
// barrier + per-block acquire fence -- proven sync structure, untouched)
// plus ONLY two dataflow changes (R20 post-mortem: R20 bundled these with a
// new 64-block barrier and hung; every hang this session coincides with a
// sync edit, so the sync is NOT touched here):
//  1) b-ring -> 3-buffer batch-of-4 STATIC preloads (bb[3][4][2], all
//     indices compile-time after unroll). Theory under test: the modular
//     ring (br[(k0+5)%6]) defeats hipcc's vmcnt accounting -> near-vmcnt(0)
//     waits before each k0's MFMAs -> full memory round trip per k0
//     (~1300 cyc measured vs ~90 ideal). Static names let the compiler
//     count waits exactly; 16 loads in flight, 8-k0 lookahead.
//  2) Qp gate constants hoisted to registers once (qall[4][3], 48 VGPR,
//     fence-immune); x loads issue at step start, consumed only in the
//     epilogue. Kills the per-step x->Qp dependent gather chain.
constexpr int kH = 1024;
constexpr int kB = 1024;
constexpr int kS = 128;
constexpr int kT = 127;
constexpr int kE = 6;
constexpr int kV = 3;
constexpr int kC = 10;

typedef short s16x8 __attribute__((ext_vector_type(8)));
typedef short s16x4 __attribute__((ext_vector_type(4)));
typedef float f32x4 __attribute__((ext_vector_type(4)));
typedef int   i32x2 __attribute__((ext_vector_type(2)));
typedef int   i32x4 __attribute__((ext_vector_type(4)));
typedef unsigned short u16;

// explicit global-address-space load pointers (vmcnt-only global_load)
typedef const __attribute__((address_space(1))) s16x8* gas_s16x8;
typedef const __attribute__((address_space(1))) f32x4* gas_f32x4;
typedef const __attribute__((address_space(1))) int*   gas_int;

__device__ __forceinline__ float b2f(u16 u) {
    return __uint_as_float(((unsigned)u) << 16);
}
__device__ __forceinline__ u16 f2b(float f) {
    unsigned u = __float_as_uint(f);
    return (u16)((u + 0x7FFFu + ((u >> 16) & 1u)) >> 16);   // RNE
}
__device__ __forceinline__ float sigmoid_fast(float x) {
    return 1.0f / (1.0f + __expf(-x));
}
__device__ __forceinline__ float tanh_fast(float x) {
    return 2.0f / (1.0f + __expf(-2.0f * x)) - 1.0f;
}
__device__ __forceinline__ float clamp30(float x) {
    return fminf(fmaxf(x, -30.0f), 30.0f);
}

__device__ __forceinline__ void async_copy16(const u16* g, u16* l) {
    __builtin_amdgcn_global_load_lds(
        (const __attribute__((address_space(1))) void*)g,
        (__attribute__((address_space(3))) void*)l, 16, 0, 0);
}

// ---------------------------------------------------------------------------
// Prep 1: weights fp32 -> bf16, frag-major (identical to R8..R19):
//   grp = (((by*4 + kc)*4 + g)*8 + k0)*64 + lane
//   wsw[grp*8 + j] = W_g[by*16 + (lane&15)][kc*256 + k0*32 + (lane>>4)*8 + j]
// ---------------------------------------------------------------------------
__global__ __launch_bounds__(256) void prep_weights(
    const float* __restrict__ Wgh, const float* __restrict__ Wih,
    const float* __restrict__ Wfh, const float* __restrict__ Woh,
    u16* __restrict__ wsw)
{
    unsigned grp = blockIdx.x * 256 + threadIdx.x;    // 0 .. 2^19-1
    const int lane = grp & 63;
    const int lm   = lane & 15;
    const int quad = lane >> 4;
    const int k0   = (grp >> 6) & 7;
    const int g    = (grp >> 9) & 3;
    const int kc   = (grp >> 11) & 3;
    const int by   = grp >> 13;                       // 0..63
    const float* src = (g == 0) ? Wgh : (g == 1) ? Wih : (g == 2) ? Wfh : Woh;
    const int row = by * 16 + lm;
    const int k   = kc * 256 + k0 * 32 + quad * 8;
    f32x4 v0 = *(const f32x4*)(src + (size_t)row * kH + k);
    f32x4 v1 = *(const f32x4*)(src + (size_t)row * kH + k + 4);
    s16x8 o;
#pragma unroll
    for (int j = 0; j < 4; ++j) o[j] = (short)f2b(v0[j]);
#pragma unroll
    for (int j = 0; j < 4; ++j) o[4 + j] = (short)f2b(v1[j]);
    *(s16x8*)(wsw + (size_t)grp * 8) = o;
}

// ---------------------------------------------------------------------------
// Prep 2: transpose h0 (H,B) fp32 -> hA (B,H) bf16; c0 (H,B) -> cT (B,H) fp32.
// ---------------------------------------------------------------------------
__global__ __launch_bounds__(1024) void prep_hc(
    const float* __restrict__ h0, const float* __restrict__ c0,
    u16* __restrict__ hA, float* __restrict__ cT)
{
    __shared__ float th[32][33];
    __shared__ float tc[32][33];
    int b = blockIdx.x * 32 + threadIdx.x;
    int h = blockIdx.y * 32 + threadIdx.y;
    th[threadIdx.y][threadIdx.x] = h0[(size_t)h * kB + b];
    tc[threadIdx.y][threadIdx.x] = c0[(size_t)h * kB + b];
    __syncthreads();
    int ob = blockIdx.x * 32 + threadIdx.y;
    int oh = blockIdx.y * 32 + threadIdx.x;
    hA[(size_t)ob * kH + oh] = f2b(th[threadIdx.x][threadIdx.y]);
    cT[(size_t)ob * kH + oh] = tc[threadIdx.x][threadIdx.y];
}

// ---------------------------------------------------------------------------
// Prep 3: gate constants repacked as f32x4 (unchanged), plus zeroing the
// barrier flags (re-zeroed every graph replay, stream-ordered before the
// persistent kernel).
// ---------------------------------------------------------------------------
__global__ __launch_bounds__(256) void prep_q(
    const float* __restrict__ Wgx, const float* __restrict__ Wix,
    const float* __restrict__ Wfx, const float* __restrict__ Wox,
    const float* __restrict__ bg,  const float* __restrict__ bi,
    const float* __restrict__ bf_, const float* __restrict__ bo,
    const float* __restrict__ emb, float* __restrict__ Qp,
    int* __restrict__ flags)
{
    int tid = blockIdx.x * blockDim.x + threadIdx.x;   // 0..4095
    if (tid < 512) flags[tid] = 0;
    if (tid >= 4096) return;
    int g   = tid >> 10;
    int hr4 = (tid & 1023) >> 2;
    int v   = tid & 3;
    const float* Wx = (g == 0) ? Wgx : (g == 1) ? Wix : (g == 2) ? Wfx : Wox;
    const float* bb = (g == 0) ? bg  : (g == 1) ? bi  : (g == 2) ? bf_ : bo;
    f32x4 o;
#pragma unroll
    for (int reg = 0; reg < 4; ++reg) {
        int row = hr4 * 4 + reg;
        float s = bb[row];
        if (v < kV) {
#pragma unroll
            for (int e = 0; e < kE; ++e) s += Wx[row * kE + e] * emb[v * kE + e];
        }
        o[reg] = s;
    }
    *(f32x4*)(Qp + (size_t)tid * 4) = o;
}

// batch loader: fills bb[BI] with k0 = BASE..BASE+3 (8 global loads)
#define LOADB(BI, BASE)                                                     \
  _Pragma("unroll")                                                         \
  for (int j = 0; j < 4; ++j) {                                             \
    bb[BI][j][0] = *(gas_s16x8)(hrow0 + ((BASE) + j) * 32);                 \
    bb[BI][j][1] = *(gas_s16x8)(hrow1 + ((BASE) + j) * 32);                 \
  }

// ---------------------------------------------------------------------------
// Persistent LSTM, LDS-resident weights: all 127 timesteps in one launch.
// Grid 256 x 512 thr (1 block/CU, 8 waves). Block tile: 16 h-rows x 4 gates
// x 256 cols; wave w: cols [bx*256 + 32w, +32) (nt=2).
// XCD swizzle: xcd=blk&7, slot=blk>>3 (0..31), by=xcd*8+(slot&7) (0..63),
// bx=slot>>3 (0..3).
// Weights: full 128 KB by-slice staged to LDS once at t=0; K-loop has no
// global staging and no barriers. Barrier/fence identical to R19.
// ---------------------------------------------------------------------------
__global__ __launch_bounds__(512, 2) void lstm_persist(
    const u16* __restrict__ wsw, const float* __restrict__ Qp,
    const int* __restrict__ x,
    short* __restrict__ hA, short* __restrict__ hB,
    const float* __restrict__ cT, int* __restrict__ flags)
{
    __shared__ u16 wlds[65536];   // 128 KB, resident all 127 steps

    const int tid  = threadIdx.x;
    const int lane = tid & 63;
    const int wave = tid >> 6;              // 0..7
    const int lm   = lane & 15;
    const int quad = lane >> 4;
    const int blk  = blockIdx.x;            // 0..255
    const int xcd  = blk & 7;
    const int slot = blk >> 3;              // 0..31
    const int by   = xcd * 8 + (slot & 7);  // 0..63
    const int bx   = slot >> 3;             // 0..3
    const int r0 = by * 16;
    const int c0 = bx * 256 + wave * 32;

    const u16* wswblk = wsw + (size_t)by * 65536;

    // ---- stage the whole weight slice once (async, 128 KB) ----
#pragma unroll
    for (int rr = 0; rr < 16; ++rr) {
        const int ub = wave * 8192 + rr * 512;   // shorts
        async_copy16(wswblk + ub + lane * 8, &wlds[ub]);
    }

    // ---- persistent c state + gate constants, in registers 127 steps ----
    f32x4 creg[2];
#pragma unroll
    for (int nt = 0; nt < 2; ++nt)
        creg[nt] = *(gas_f32x4)(cT +
            (size_t)(c0 + nt * 16 + lm) * kH + r0 + quad * 4);

    // qall[g][v]: all 3 vocab variants of the gate constant vector (48 VGPR,
    // fence-immune). Selected per-step by vv in the epilogue (no memory).
    f32x4 qall[4][3];
#pragma unroll
    for (int g = 0; g < 4; ++g)
#pragma unroll
        for (int v = 0; v < 3; ++v)
            qall[g][v] = *(gas_f32x4)(Qp +
                (size_t)(((g * 256 + by * 4 + quad) * 4 + v) * 4));

    const int* xp0 = x + (size_t)(c0 + lm) * kS;
    const int* xp1 = x + (size_t)(c0 + 16 + lm) * kS;
    const int koff = quad * 8;

    asm volatile("s_waitcnt vmcnt(0)" ::: "memory");
    __syncthreads();   // weights resident from here on

#pragma unroll 1
    for (int t = 0; t < kT; ++t) {
        const short* hin  = (t & 1) ? hB : hA;
        short*       hout = (t & 1) ? hA : hB;

        const short* hrow0 = hin + (size_t)(c0 + lm) * kH + koff;
        const short* hrow1 = hin + (size_t)(c0 + 16 + lm) * kH + koff;

        // ---- b prologue: batches 0,1 (16 loads in flight) ----
        s16x8 bb[3][4][2];   // [batch%3][j][nt] -- all static after unroll
        LOADB(0, 0)
        LOADB(1, 4)

        // ---- x loads: issue now, consumed only in the epilogue ----
        int xv0 = *(gas_int)(xp0 + t);
        int xv1 = *(gas_int)(xp1 + t);

        f32x4 acc[4][2];
        const f32x4 zero = {0.f, 0.f, 0.f, 0.f};
#pragma unroll
        for (int g = 0; g < 4; ++g)
#pragma unroll
            for (int n = 0; n < 2; ++n) acc[g][n] = zero;

        // ---- main K loop: 32 x (4 ds_read_b128 + 8 MFMA); batch-of-4 b
        //      prefetch, 8-k0 lookahead, static buffer indices ----
#pragma unroll
        for (int k0 = 0; k0 < 32; ++k0) {
            if ((k0 & 3) == 0 && k0 + 8 < 32) {
                const int nb = ((k0 >> 2) + 2) % 3;
                LOADB(nb, k0 + 8)
            }
            const int cub = (k0 >> 2) % 3;
            const int ji  = k0 & 3;
            const int cb  = (k0 >> 3) * 16384;        // K-chunk base (shorts)
#pragma unroll
            for (int g = 0; g < 4; ++g) {
                const int f = cb + ((g * 8 + (k0 & 7)) * 64 + lane) * 8;
                s16x8 a = *(const s16x8*)&wlds[f];
                acc[g][0] = __builtin_amdgcn_mfma_f32_16x16x32_bf16(a, bb[cub][ji][0], acc[g][0], 0, 0, 0);
                acc[g][1] = __builtin_amdgcn_mfma_f32_16x16x32_bf16(a, bb[cub][ji][1], acc[g][1], 0, 0, 0);
            }
        }

        // ---- epilogue: ALU + coherent h store. C/D: col=lane&15, row=quad*4+reg
        int vv[2];
        vv[0] = (xv0 < 0) ? 0 : (xv0 > kV - 1) ? (kV - 1) : xv0;
        vv[1] = (xv1 < 0) ? 0 : (xv1 > kV - 1) ? (kV - 1) : xv1;
#pragma unroll
        for (int nt = 0; nt < 2; ++nt) {
            const int c = c0 + nt * 16 + lm;
            const int rb = r0 + quad * 4;
            f32x4 qs[4];
#pragma unroll
            for (int g = 0; g < 4; ++g)
                qs[g] = (vv[nt] == 0) ? qall[g][0]
                      : (vv[nt] == 1) ? qall[g][1] : qall[g][2];
            f32x4 cnew;
            s16x4 hnew;
#pragma unroll
            for (int reg = 0; reg < 4; ++reg) {
                float pg = clamp30(acc[0][nt][reg] + qs[0][reg]);
                float pi = clamp30(acc[1][nt][reg] + qs[1][reg]);
                float pf = clamp30(acc[2][nt][reg] + qs[2][reg]);
                float po = clamp30(acc[3][nt][reg] + qs[3][reg]);
                float gg = tanh_fast(pg);
                float ii = sigmoid_fast(pi);
                float ff = sigmoid_fast(pf);
                float oo = sigmoid_fast(po);
                float c2 = gg * ii + creg[nt][reg] * ff;
                c2 = fminf(fmaxf(c2, -200.0f), 200.0f);
                cnew[reg] = c2;
                hnew[reg] = (short)f2b(tanh_fast(c2) * oo);
            }
            creg[nt] = cnew;
            i32x2 hv;
            __builtin_memcpy(&hv, &hnew, 8);
            short* hp = hout + (size_t)c * kH + rb;
            // write-through to L3: device-visible once vmcnt drains.
            asm volatile("global_store_dwordx2 %0, %1, off sc0 sc1"
                         :: "v"(hp), "v"(hv) : "memory");
        }

        if (t < kT - 1) {
            // ---- grid barrier across 256 blocks (R19-identical) ----
            asm volatile("s_waitcnt vmcnt(0)" ::: "memory");  // own h stores done
            __syncthreads();                                  // whole block done
            if (tid < 64) {
                if (tid == 0) {
                    int* fp = flags + blk;
                    int fv = t + 1;
                    asm volatile("global_store_dword %0, %1, off sc0 sc1\n\t"
                                 "s_waitcnt vmcnt(0)"
                                 :: "v"(fp), "v"(fv) : "memory");
                }
                const int* fp = flags + lane * 4;   // 64 lanes x 4 = all 256
                for (;;) {
                    i32x4 fa;
                    asm volatile(
                        "global_load_dwordx4 %0, %1, off sc0 sc1\n\t"
                        "s_waitcnt vmcnt(0)"
                        : "=&v"(fa) : "v"(fp) : "memory");
                    int ok = (fa.x > t) & (fa.y > t) & (fa.z > t) & (fa.w > t);
                    if (__all(ok)) break;
                    __builtin_amdgcn_s_sleep(1);
                }
                // ONE acquire per block per step: invalidates this CU's L1 +
                // this XCD's L2 so next step's cached h reads are fresh.
                // Weights (LDS) and qall/creg (registers) are immune.
                __builtin_amdgcn_fence(__ATOMIC_ACQUIRE, "agent");
            }
            __syncthreads();
        }
    }
}

// ---------------------------------------------------------------------------
// Logits: p[b][cls] = h[b,:] . W_ph[cls,:] + b_p[cls]; log_softmax over 10.
// ---------------------------------------------------------------------------
__global__ __launch_bounds__(256) void logits_kernel(
    const u16* __restrict__ hT, const float* __restrict__ Wph,
    const float* __restrict__ bp, float* __restrict__ out)
{
    const int wave = threadIdx.x >> 6;
    const int lane = threadIdx.x & 63;
    const int b = blockIdx.x * 4 + wave;

    const u16* hp = hT + (size_t)b * kH + lane * 16;
    float hf[16];
#pragma unroll
    for (int j = 0; j < 16; ++j) hf[j] = b2f(hp[j]);

    float p[kC];
#pragma unroll
    for (int cls = 0; cls < kC; ++cls) {
        const float* wp = Wph + (size_t)cls * kH + lane * 16;
        float s = 0.f;
#pragma unroll
        for (int j = 0; j < 16; ++j) s += hf[j] * wp[j];
#pragma unroll
        for (int off = 1; off < 64; off <<= 1) s += __shfl_xor(s, off, 64);
        p[cls] = fminf(fmaxf(s + bp[cls], -1.0e4f), 1.0e4f);
    }

    float m = p[0];
#pragma unroll
    for (int cls = 1; cls < kC; ++cls) m = fmaxf(m, p[cls]);
    float se = 0.f;
#pragma unroll
    for (int cls = 0; cls < kC; ++cls) se += __expf(p[cls] - m);
    float l = m + __logf(se);

    if (lane < kC) {
        float myp = p[0];
#pragma unroll
        for (int cls = 1; cls < kC; ++cls)
            if (lane == cls) myp = p[cls];
        out[(size_t)b * kC + lane] = myp - l;
    }
}

// ---------------------------------------------------------------------------
extern "C" void kernel_launch(void* const* d_in, const int* in_sizes, int n_in,
                              void* d_out, int out_size, void* d_ws, size_t ws_size,
                              hipStream_t stream)
{
    const int*   x   = (const int*)  d_in[0];
    const float* emb = (const float*)d_in[1];
    const float* Wgx = (const float*)d_in[2];
    const float* Wgh = (const float*)d_in[3];
    const float* bg  = (const float*)d_in[4];
    const float* Wix = (const float*)d_in[5];
    const float* Wih = (const float*)d_in[6];
    const float* bi  = (const float*)d_in[7];
    const float* Wfx = (const float*)d_in[8];
    const float* Wfh = (const float*)d_in[9];
    const float* bf_ = (const float*)d_in[10];
    const float* Wox = (const float*)d_in[11];
    const float* Woh = (const float*)d_in[12];
    const float* bo  = (const float*)d_in[13];
    const float* Wph = (const float*)d_in[14];
    const float* bp  = (const float*)d_in[15];
    const float* h0  = (const float*)d_in[16];
    const float* c0  = (const float*)d_in[17];

    char* ws = (char*)d_ws;
    float* Qp  = (float*)ws;                              // 64 KB
    u16*   hA  = (u16*)(ws + (64 << 10));                 // 2 MB
    u16*   hB  = hA + (size_t)kB * kH;                    // 2 MB
    float* cT  = (float*)(hB + (size_t)kB * kH);          // 4 MB
    u16*   wsw = (u16*)(cT + (size_t)kB * kH);            // 8 MB
    int*   flags = (int*)(wsw + (size_t)64 * 65536);      // 2 KB (total ~16.07 MB)

    prep_weights<<<dim3(2048), dim3(256), 0, stream>>>(Wgh, Wih, Wfh, Woh, wsw);
    prep_hc<<<dim3(kB / 32, kH / 32), dim3(32, 32), 0, stream>>>(h0, c0, hA, cT);
    prep_q<<<dim3(16), dim3(256), 0, stream>>>(Wgx, Wix, Wfx, Wox, bg, bi, bf_, bo,
                                               emb, Qp, flags);

    lstm_persist<<<dim3(256), dim3(512), 0, stream>>>(
        wsw, Qp, x, (short*)hA, (short*)hB, cT, flags);

    // 127 steps: t=126 (even) wrote hB.
    logits_kernel<<<dim3(kB / 4), dim3(256), 0, stream>>>(hB, Wph, bp, (float*)d_out);
}

// Round 10
// 2670.119 us; speedup vs baseline: 1.0980x; 1.0980x over previous
//
#include <hip/hip_runtime.h>

// LSTM: H=1024, B=1024, S=128 (T=127 steps), E=6, V=3, C=10.
// R22 = R15 sync structure VERBATIM (passed, best total 2522 us: pair-local
// 64-flag barrier, ONE leader buffer_inv sc1 per XCD per step, vL1-only inv
// for the rest) + R21 dataflow VERBATIM (passed: qall[4][3] register hoist
// of the gate constants, static 3-buffer batch b-path, early x loads).
// Rationale: 9 rounds established (a) the b-path micro-structure doesn't
// move step time (ring/static/AS1/warm-L2 all equal), (b) sync edits are
// the only hang source (R17/R20), (c) R15's pair-locality cut FETCH 4x and
// gave the best total. This merge combines the two proven halves with zero
// new sync topology.
constexpr int kH = 1024;
constexpr int kB = 1024;
constexpr int kS = 128;
constexpr int kT = 127;
constexpr int kE = 6;
constexpr int kV = 3;
constexpr int kC = 10;

typedef short s16x8 __attribute__((ext_vector_type(8)));
typedef short s16x4 __attribute__((ext_vector_type(4)));
typedef float f32x4 __attribute__((ext_vector_type(4)));
typedef int   i32x2 __attribute__((ext_vector_type(2)));
typedef unsigned short u16;

// explicit global-address-space load pointers (vmcnt-only global_load)
typedef const __attribute__((address_space(1))) s16x8* gas_s16x8;
typedef const __attribute__((address_space(1))) f32x4* gas_f32x4;
typedef const __attribute__((address_space(1))) int*   gas_int;

__device__ __forceinline__ float b2f(u16 u) {
    return __uint_as_float(((unsigned)u) << 16);
}
__device__ __forceinline__ u16 f2b(float f) {
    unsigned u = __float_as_uint(f);
    return (u16)((u + 0x7FFFu + ((u >> 16) & 1u)) >> 16);   // RNE
}
__device__ __forceinline__ float sigmoid_fast(float x) {
    return 1.0f / (1.0f + __expf(-x));
}
__device__ __forceinline__ float tanh_fast(float x) {
    return 2.0f / (1.0f + __expf(-2.0f * x)) - 1.0f;
}
__device__ __forceinline__ float clamp30(float x) {
    return fminf(fmaxf(x, -30.0f), 30.0f);
}

__device__ __forceinline__ void async_copy16(const u16* g, u16* l) {
    __builtin_amdgcn_global_load_lds(
        (const __attribute__((address_space(1))) void*)g,
        (__attribute__((address_space(3))) void*)l, 16, 0, 0);
}

// ---------------------------------------------------------------------------
// Prep 1: weights fp32 -> bf16, frag-major (identical to R8..R21):
//   grp = (((by*4 + kc)*4 + g)*8 + k0)*64 + lane
//   wsw[grp*8 + j] = W_g[by*16 + (lane&15)][kc*256 + k0*32 + (lane>>4)*8 + j]
// ---------------------------------------------------------------------------
__global__ __launch_bounds__(256) void prep_weights(
    const float* __restrict__ Wgh, const float* __restrict__ Wih,
    const float* __restrict__ Wfh, const float* __restrict__ Woh,
    u16* __restrict__ wsw)
{
    unsigned grp = blockIdx.x * 256 + threadIdx.x;    // 0 .. 2^19-1
    const int lane = grp & 63;
    const int lm   = lane & 15;
    const int quad = lane >> 4;
    const int k0   = (grp >> 6) & 7;
    const int g    = (grp >> 9) & 3;
    const int kc   = (grp >> 11) & 3;
    const int by   = grp >> 13;                       // 0..63
    const float* src = (g == 0) ? Wgh : (g == 1) ? Wih : (g == 2) ? Wfh : Woh;
    const int row = by * 16 + lm;
    const int k   = kc * 256 + k0 * 32 + quad * 8;
    f32x4 v0 = *(const f32x4*)(src + (size_t)row * kH + k);
    f32x4 v1 = *(const f32x4*)(src + (size_t)row * kH + k + 4);
    s16x8 o;
#pragma unroll
    for (int j = 0; j < 4; ++j) o[j] = (short)f2b(v0[j]);
#pragma unroll
    for (int j = 0; j < 4; ++j) o[4 + j] = (short)f2b(v1[j]);
    *(s16x8*)(wsw + (size_t)grp * 8) = o;
}

// ---------------------------------------------------------------------------
// Prep 2: transpose h0 (H,B) fp32 -> hA (B,H) bf16; c0 (H,B) -> cT (B,H) fp32.
// ---------------------------------------------------------------------------
__global__ __launch_bounds__(1024) void prep_hc(
    const float* __restrict__ h0, const float* __restrict__ c0,
    u16* __restrict__ hA, float* __restrict__ cT)
{
    __shared__ float th[32][33];
    __shared__ float tc[32][33];
    int b = blockIdx.x * 32 + threadIdx.x;
    int h = blockIdx.y * 32 + threadIdx.y;
    th[threadIdx.y][threadIdx.x] = h0[(size_t)h * kB + b];
    tc[threadIdx.y][threadIdx.x] = c0[(size_t)h * kB + b];
    __syncthreads();
    int ob = blockIdx.x * 32 + threadIdx.y;
    int oh = blockIdx.y * 32 + threadIdx.x;
    hA[(size_t)ob * kH + oh] = f2b(th[threadIdx.x][threadIdx.y]);
    cT[(size_t)ob * kH + oh] = tc[threadIdx.x][threadIdx.y];
}

// ---------------------------------------------------------------------------
// Prep 3: gate constants repacked as f32x4 (unchanged), plus zeroing the
// control block (flags[256] @0, release[8] @256, xccCnt[8] @264) every
// graph replay, stream-ordered before the persistent kernel.
// ---------------------------------------------------------------------------
__global__ __launch_bounds__(256) void prep_q(
    const float* __restrict__ Wgx, const float* __restrict__ Wix,
    const float* __restrict__ Wfx, const float* __restrict__ Wox,
    const float* __restrict__ bg,  const float* __restrict__ bi,
    const float* __restrict__ bf_, const float* __restrict__ bo,
    const float* __restrict__ emb, float* __restrict__ Qp,
    int* __restrict__ ctrl)
{
    int tid = blockIdx.x * blockDim.x + threadIdx.x;   // 0..4095
    if (tid < 512) ctrl[tid] = 0;
    if (tid >= 4096) return;
    int g   = tid >> 10;
    int hr4 = (tid & 1023) >> 2;
    int v   = tid & 3;
    const float* Wx = (g == 0) ? Wgx : (g == 1) ? Wix : (g == 2) ? Wfx : Wox;
    const float* bb = (g == 0) ? bg  : (g == 1) ? bi  : (g == 2) ? bf_ : bo;
    f32x4 o;
#pragma unroll
    for (int reg = 0; reg < 4; ++reg) {
        int row = hr4 * 4 + reg;
        float s = bb[row];
        if (v < kV) {
#pragma unroll
            for (int e = 0; e < kE; ++e) s += Wx[row * kE + e] * emb[v * kE + e];
        }
        o[reg] = s;
    }
    *(f32x4*)(Qp + (size_t)tid * 4) = o;
}

// batch loader: fills bb[BI] with k0 = BASE..BASE+3 (8 global loads)
#define LOADB(BI, BASE)                                                     \
  _Pragma("unroll")                                                         \
  for (int j = 0; j < 4; ++j) {                                             \
    bb[BI][j][0] = *(gas_s16x8)(hrow0 + ((BASE) + j) * 32);                 \
    bb[BI][j][1] = *(gas_s16x8)(hrow1 + ((BASE) + j) * 32);                 \
  }

// ---------------------------------------------------------------------------
// Persistent LSTM: 256 blocks x 512 thr (1 block/CU, 8 waves), weights
// LDS-resident. Block identity from HW: xcc = XCC_ID, rank = arrival order
// within XCD. q = (xcc&1)*32 + rank (row-group, 16 rows x 4 gates),
// p = xcc>>1 (col-group, 256 cols). Wave w: cols [p*256+32w, +32) (nt=2).
// Per-step sync per XCD pair: 64 flags; rank-0 leader per XCD does the
// single buffer_inv sc1 + release. (R15 sync, verbatim.)
// ---------------------------------------------------------------------------
__global__ __launch_bounds__(512, 2) void lstm_persist(
    const u16* __restrict__ wsw, const float* __restrict__ Qp,
    const int* __restrict__ x,
    short* __restrict__ hA, short* __restrict__ hB,
    const float* __restrict__ cT, int* __restrict__ ctrl)
{
    __shared__ u16 wlds[65536];   // 128 KB, resident all 127 steps
    __shared__ int sh_ids[2];

    const int tid  = threadIdx.x;
    const int lane = tid & 63;
    const int wave = tid >> 6;              // 0..7
    const int lm   = lane & 15;
    const int quad = lane >> 4;

    // ---- runtime identity: XCD id + arrival rank within XCD ----
    if (tid == 0) {
        unsigned xccr;
        asm volatile("s_getreg_b32 %0, hwreg(HW_REG_XCC_ID)" : "=s"(xccr));
        int rank = atomicAdd(ctrl + 264 + (xccr & 7), 1);
        sh_ids[0] = (int)(xccr & 7);
        sh_ids[1] = rank;
    }
    __syncthreads();
    const int xcc  = sh_ids[0];
    const int rank = sh_ids[1];             // 0..31 within XCD
    const int p    = xcc >> 1;              // col-group 0..3 (XCD pair)
    const int q    = (xcc & 1) * 32 + rank; // row-group 0..63 within pair
    const bool leader = (rank == 0);
    const int r0 = q * 16;
    const int c0 = p * 256 + wave * 32;

    int* flags   = ctrl;            // [p*64 + q], monotonic step counters
    int* release = ctrl + 256;      // [xcc]

    const u16* wswblk = wsw + (size_t)q * 65536;

    // ---- stage the whole weight slice once (async, 128 KB) ----
#pragma unroll
    for (int rr = 0; rr < 16; ++rr) {
        const int ub = wave * 8192 + rr * 512;   // shorts
        async_copy16(wswblk + ub + lane * 8, &wlds[ub]);
    }

    // ---- persistent c state + gate constants, in registers 127 steps ----
    f32x4 creg[2];
#pragma unroll
    for (int nt = 0; nt < 2; ++nt)
        creg[nt] = *(gas_f32x4)(cT +
            (size_t)(c0 + nt * 16 + lm) * kH + r0 + quad * 4);

    // qall[g][v]: all 3 vocab variants of the gate constant vector (48 VGPR,
    // fence-immune). Selected per-step by vv in the epilogue (no memory).
    f32x4 qall[4][3];
#pragma unroll
    for (int g = 0; g < 4; ++g)
#pragma unroll
        for (int v = 0; v < 3; ++v)
            qall[g][v] = *(gas_f32x4)(Qp +
                (size_t)(((g * 256 + q * 4 + quad) * 4 + v) * 4));

    const int* xp0 = x + (size_t)(c0 + lm) * kS;
    const int* xp1 = x + (size_t)(c0 + 16 + lm) * kS;
    const int koff = quad * 8;

    asm volatile("s_waitcnt vmcnt(0)" ::: "memory");
    __syncthreads();   // weights resident from here on

#pragma unroll 1
    for (int t = 0; t < kT; ++t) {
        const short* hin  = (t & 1) ? hB : hA;
        short*       hout = (t & 1) ? hA : hB;

        const short* hrow0 = hin + (size_t)(c0 + lm) * kH + koff;
        const short* hrow1 = hin + (size_t)(c0 + 16 + lm) * kH + koff;

        // ---- b prologue: batches 0,1 (16 loads in flight) ----
        s16x8 bb[3][4][2];   // [batch%3][j][nt] -- all static after unroll
        LOADB(0, 0)
        LOADB(1, 4)

        // ---- x loads: issue now, consumed only in the epilogue ----
        int xv0 = *(gas_int)(xp0 + t);
        int xv1 = *(gas_int)(xp1 + t);

        f32x4 acc[4][2];
        const f32x4 zero = {0.f, 0.f, 0.f, 0.f};
#pragma unroll
        for (int g = 0; g < 4; ++g)
#pragma unroll
            for (int n = 0; n < 2; ++n) acc[g][n] = zero;

        // ---- main K loop: 32 x (4 ds_read_b128 + 8 MFMA); batch-of-4 b
        //      prefetch, 8-k0 lookahead, static buffer indices ----
#pragma unroll
        for (int k0 = 0; k0 < 32; ++k0) {
            if ((k0 & 3) == 0 && k0 + 8 < 32) {
                const int nb = ((k0 >> 2) + 2) % 3;
                LOADB(nb, k0 + 8)
            }
            const int cub = (k0 >> 2) % 3;
            const int ji  = k0 & 3;
            const int cb  = (k0 >> 3) * 16384;        // K-chunk base (shorts)
#pragma unroll
            for (int g = 0; g < 4; ++g) {
                const int f = cb + ((g * 8 + (k0 & 7)) * 64 + lane) * 8;
                s16x8 a = *(const s16x8*)&wlds[f];
                acc[g][0] = __builtin_amdgcn_mfma_f32_16x16x32_bf16(a, bb[cub][ji][0], acc[g][0], 0, 0, 0);
                acc[g][1] = __builtin_amdgcn_mfma_f32_16x16x32_bf16(a, bb[cub][ji][1], acc[g][1], 0, 0, 0);
            }
        }

        // ---- epilogue: ALU + coherent h store. C/D: col=lane&15, row=quad*4+reg
        int vv[2];
        vv[0] = (xv0 < 0) ? 0 : (xv0 > kV - 1) ? (kV - 1) : xv0;
        vv[1] = (xv1 < 0) ? 0 : (xv1 > kV - 1) ? (kV - 1) : xv1;
#pragma unroll
        for (int nt = 0; nt < 2; ++nt) {
            const int c = c0 + nt * 16 + lm;
            const int rb = r0 + quad * 4;
            f32x4 qs[4];
#pragma unroll
            for (int g = 0; g < 4; ++g)
                qs[g] = (vv[nt] == 0) ? qall[g][0]
                      : (vv[nt] == 1) ? qall[g][1] : qall[g][2];
            f32x4 cnew;
            s16x4 hnew;
#pragma unroll
            for (int reg = 0; reg < 4; ++reg) {
                float pg = clamp30(acc[0][nt][reg] + qs[0][reg]);
                float pi = clamp30(acc[1][nt][reg] + qs[1][reg]);
                float pf = clamp30(acc[2][nt][reg] + qs[2][reg]);
                float po = clamp30(acc[3][nt][reg] + qs[3][reg]);
                float gg = tanh_fast(pg);
                float ii = sigmoid_fast(pi);
                float ff = sigmoid_fast(pf);
                float oo = sigmoid_fast(po);
                float c2 = gg * ii + creg[nt][reg] * ff;
                c2 = fminf(fmaxf(c2, -200.0f), 200.0f);
                cnew[reg] = c2;
                hnew[reg] = (short)f2b(tanh_fast(c2) * oo);
            }
            creg[nt] = cnew;
            i32x2 hv;
            __builtin_memcpy(&hv, &hnew, 8);
            short* hp = hout + (size_t)c * kH + rb;
            // write-through: device-visible once vmcnt drains.
            asm volatile("global_store_dwordx2 %0, %1, off sc0 sc1"
                         :: "v"(hp), "v"(hv) : "memory");
        }

        if (t < kT - 1) {
            // ---- pair-local barrier + single L2 inv per XCD (R15 verbatim) ----
            asm volatile("s_waitcnt vmcnt(0)" ::: "memory");  // h stores done
            __syncthreads();                                  // block done
            if (tid == 0) {
                int* fp = flags + p * 64 + q;
                int fv = t + 1;
                asm volatile("global_store_dword %0, %1, off sc0 sc1\n\t"
                             "s_waitcnt vmcnt(0)"
                             :: "v"(fp), "v"(fv) : "memory");
            }
            if (leader && tid < 64) {
                // leader wave0: wait for the pair's 64 flags
                const int* fp = flags + p * 64 + lane;
                for (;;) {
                    int fvv;
                    asm volatile(
                        "global_load_dword %0, %1, off sc0 sc1\n\t"
                        "s_waitcnt vmcnt(0)"
                        : "=v"(fvv) : "v"(fp) : "memory");
                    if (__all(fvv > t)) break;
                    __builtin_amdgcn_s_sleep(1);
                }
                if (lane == 0) {
                    // one L2 invalidate for this XCD, then release
                    asm volatile("buffer_inv sc1\n\t"
                                 "s_waitcnt vmcnt(0)" ::: "memory");
                    int* rp = release + xcc;
                    int rv = t + 1;
                    asm volatile("global_store_dword %0, %1, off sc0 sc1\n\t"
                                 "s_waitcnt vmcnt(0)"
                                 :: "v"(rp), "v"(rv) : "memory");
                }
            }
            if (tid < 64) {
                // everyone: wait own XCD's release, then vL1-only invalidate
                const int* rp = release + xcc;
                for (;;) {
                    int rvv;
                    asm volatile(
                        "global_load_dword %0, %1, off sc0 sc1\n\t"
                        "s_waitcnt vmcnt(0)"
                        : "=v"(rvv) : "v"(rp) : "memory");
                    if (__all(rvv > t)) break;
                    __builtin_amdgcn_s_sleep(1);
                }
                asm volatile("buffer_inv" ::: "memory");   // vL1 only
            }
            __syncthreads();
        }
    }
}

// ---------------------------------------------------------------------------
// Logits: p[b][cls] = h[b,:] . W_ph[cls,:] + b_p[cls]; log_softmax over 10.
// ---------------------------------------------------------------------------
__global__ __launch_bounds__(256) void logits_kernel(
    const u16* __restrict__ hT, const float* __restrict__ Wph,
    const float* __restrict__ bp, float* __restrict__ out)
{
    const int wave = threadIdx.x >> 6;
    const int lane = threadIdx.x & 63;
    const int b = blockIdx.x * 4 + wave;

    const u16* hp = hT + (size_t)b * kH + lane * 16;
    float hf[16];
#pragma unroll
    for (int j = 0; j < 16; ++j) hf[j] = b2f(hp[j]);

    float p[kC];
#pragma unroll
    for (int cls = 0; cls < kC; ++cls) {
        const float* wp = Wph + (size_t)cls * kH + lane * 16;
        float s = 0.f;
#pragma unroll
        for (int j = 0; j < 16; ++j) s += hf[j] * wp[j];
#pragma unroll
        for (int off = 1; off < 64; off <<= 1) s += __shfl_xor(s, off, 64);
        p[cls] = fminf(fmaxf(s + bp[cls], -1.0e4f), 1.0e4f);
    }

    float m = p[0];
#pragma unroll
    for (int cls = 1; cls < kC; ++cls) m = fmaxf(m, p[cls]);
    float se = 0.f;
#pragma unroll
    for (int cls = 0; cls < kC; ++cls) se += __expf(p[cls] - m);
    float l = m + __logf(se);

    if (lane < kC) {
        float myp = p[0];
#pragma unroll
        for (int cls = 1; cls < kC; ++cls)
            if (lane == cls) myp = p[cls];
        out[(size_t)b * kC + lane] = myp - l;
    }
}

// ---------------------------------------------------------------------------
extern "C" void kernel_launch(void* const* d_in, const int* in_sizes, int n_in,
                              void* d_out, int out_size, void* d_ws, size_t ws_size,
                              hipStream_t stream)
{
    const int*   x   = (const int*)  d_in[0];
    const float* emb = (const float*)d_in[1];
    const float* Wgx = (const float*)d_in[2];
    const float* Wgh = (const float*)d_in[3];
    const float* bg  = (const float*)d_in[4];
    const float* Wix = (const float*)d_in[5];
    const float* Wih = (const float*)d_in[6];
    const float* bi  = (const float*)d_in[7];
    const float* Wfx = (const float*)d_in[8];
    const float* Wfh = (const float*)d_in[9];
    const float* bf_ = (const float*)d_in[10];
    const float* Wox = (const float*)d_in[11];
    const float* Woh = (const float*)d_in[12];
    const float* bo  = (const float*)d_in[13];
    const float* Wph = (const float*)d_in[14];
    const float* bp  = (const float*)d_in[15];
    const float* h0  = (const float*)d_in[16];
    const float* c0  = (const float*)d_in[17];

    char* ws = (char*)d_ws;
    float* Qp  = (float*)ws;                              // 64 KB
    u16*   hA  = (u16*)(ws + (64 << 10));                 // 2 MB
    u16*   hB  = hA + (size_t)kB * kH;                    // 2 MB
    float* cT  = (float*)(hB + (size_t)kB * kH);          // 4 MB
    u16*   wsw = (u16*)(cT + (size_t)kB * kH);            // 8 MB
    int*   ctrl = (int*)(wsw + (size_t)64 * 65536);       // 2 KB (total ~16.07 MB)

    prep_weights<<<dim3(2048), dim3(256), 0, stream>>>(Wgh, Wih, Wfh, Woh, wsw);
    prep_hc<<<dim3(kB / 32, kH / 32), dim3(32, 32), 0, stream>>>(h0, c0, hA, cT);
    prep_q<<<dim3(16), dim3(256), 0, stream>>>(Wgx, Wix, Wfx, Wox, bg, bi, bf_, bo,
                                               emb, Qp, ctrl);

    lstm_persist<<<dim3(256), dim3(512), 0, stream>>>(
        wsw, Qp, x, (short*)hA, (short*)hB, cT, ctrl);

    // 127 steps: t=126 (even) wrote hB.
    logits_kernel<<<dim3(kB / 4), dim3(256), 0, stream>>>(hB, Wph, bp, (float*)d_out);
}